// Round 2
// baseline (343.590 us; speedup 1.0000x reference)
//
#include <hip/hip_runtime.h>
#include <stdint.h>

typedef unsigned short u16;
typedef __attribute__((ext_vector_type(8))) _Float16 half8;  // 8 x f16 (4 VGPRs)
typedef __attribute__((ext_vector_type(4))) float f32x4;

#define L2E 1.4426950408889634f

// ---- sizes (compile-time constants for this problem) ----
// B=4, T=2048, D=512, H=8, DK=64; N = B*T = 8192
#define NTOK 8192
#define DIM  512
#define TT   2048

__device__ __forceinline__ u16 f2h(float f) {
  _Float16 h = (_Float16)f;  // RNE via v_cvt_f16_f32
  return __builtin_bit_cast(u16, h);
}

__device__ __forceinline__ void async16(const void* g, void* l) {
  __builtin_amdgcn_global_load_lds(
      (const __attribute__((address_space(1))) unsigned int*)g,
      (__attribute__((address_space(3))) unsigned int*)l, 16, 0, 0);
}

// ---------------- fp32 -> fp16 conversion: x (4.19M) + 4 weights (262144 each)
__global__ __launch_bounds__(256) void k_convert(
    const float* __restrict__ x, const float* __restrict__ wq,
    const float* __restrict__ wk, const float* __restrict__ wv,
    const float* __restrict__ wo, u16* __restrict__ xb) {
  size_t i = ((size_t)blockIdx.x * 256 + threadIdx.x) * 8;
  const float* src;
  u16* dst;
  size_t off;
  if (i < 4194304) {
    src = x; dst = xb; off = i;
  } else {
    size_t j = i - 4194304;
    int w = (int)(j >> 18);
    off = j & 262143;
    src = (w == 0) ? wq : (w == 1) ? wk : (w == 2) ? wv : wo;
    dst = xb + 4194304 + (size_t)w * 262144;
  }
  float4 a = *(const float4*)(src + off);
  float4 b = *(const float4*)(src + off + 4);
  uint4 pk;
  pk.x = (unsigned)f2h(a.x) | ((unsigned)f2h(a.y) << 16);
  pk.y = (unsigned)f2h(a.z) | ((unsigned)f2h(a.w) << 16);
  pk.z = (unsigned)f2h(b.x) | ((unsigned)f2h(b.y) << 16);
  pk.w = (unsigned)f2h(b.z) | ((unsigned)f2h(b.w) << 16);
  *(uint4*)(dst + off) = pk;
}

// ---------------- 128x128 NT GEMM: C[m][n] = sum_k A[m][k] * W[n][k]
// MODE 0: QKV projections (grid.z selects weight); Q,K -> head-major f16,
//         V -> transposed [bh][dk][t] f16.
// MODE 1: final output GEMM, fp32 row-major to d_out.
template <int MODE>
__global__ __launch_bounds__(256) void k_gemm(
    const u16* __restrict__ A, const u16* __restrict__ Wb,
    u16* __restrict__ Db, float* __restrict__ Df) {
  const int tid = threadIdx.x;
  const int wave = tid >> 6, lane = tid & 63;
  const int quad = lane >> 4, l16 = lane & 15;
  const int wr = wave >> 1, wc = wave & 1;
  const int m0 = blockIdx.x * 128, n0 = blockIdx.y * 128;

  const u16* W = Wb;
  u16* D = Db;
  int vmode = 0;
  if (MODE == 0) {
    int z = blockIdx.z;
    W = Wb + (size_t)z * 262144;
    D = Db + (size_t)z * 4194304;
    vmode = (z == 2);
  }

  __shared__ __align__(16) u16 As[128 * 64];
  __shared__ __align__(16) u16 Bs[128 * 64];

  f32x4 acc[4][4];
  for (int rt = 0; rt < 4; ++rt)
    for (int ct = 0; ct < 4; ++ct) acc[rt][ct] = (f32x4){0.f, 0.f, 0.f, 0.f};

  for (int kb = 0; kb < 8; ++kb) {
    const int k0 = kb * 64;
    // Stage A tile [128][64] and B tile [128][64], xor-swizzled 16B chunks.
    for (int r = 0; r < 4; ++r) {
      int cid = r * 256 + tid;
      int row = cid >> 3, cl = cid & 7, cg = cl ^ (row & 7);
      async16(A + (size_t)(m0 + row) * DIM + k0 + cg * 8,
              &As[(r * 256 + wave * 64) * 8]);
    }
    for (int r = 0; r < 4; ++r) {
      int cid = r * 256 + tid;
      int row = cid >> 3, cl = cid & 7, cg = cl ^ (row & 7);
      async16(W + (size_t)(n0 + row) * DIM + k0 + cg * 8,
              &Bs[(r * 256 + wave * 64) * 8]);
    }
    __syncthreads();
    for (int kc = 0; kc < 2; ++kc) {
      half8 af[4], bfv[4];
      for (int rt = 0; rt < 4; ++rt) {
        int row = wr * 64 + rt * 16 + l16;
        int c = (kc * 4 + quad) ^ (row & 7);
        af[rt] = *(const half8*)&As[row * 64 + c * 8];
      }
      for (int ct = 0; ct < 4; ++ct) {
        int row = wc * 64 + ct * 16 + l16;
        int c = (kc * 4 + quad) ^ (row & 7);
        bfv[ct] = *(const half8*)&Bs[row * 64 + c * 8];
      }
      for (int rt = 0; rt < 4; ++rt)
        for (int ct = 0; ct < 4; ++ct)
          acc[rt][ct] = __builtin_amdgcn_mfma_f32_16x16x32_f16(
              af[rt], bfv[ct], acc[rt][ct], 0, 0, 0);
    }
    __syncthreads();
  }

  // Epilogue. C/D layout: col = lane&15, row = quad*4 + reg.
  for (int rt = 0; rt < 4; ++rt)
    for (int ct = 0; ct < 4; ++ct)
      for (int reg = 0; reg < 4; ++reg) {
        int gm = m0 + wr * 64 + rt * 16 + quad * 4 + reg;  // token n
        int gn = n0 + wc * 64 + ct * 16 + l16;             // feature o
        float v = acc[rt][ct][reg];
        if (MODE == 1) {
          Df[(size_t)gm * DIM + gn] = v;
        } else {
          int bb = gm >> 11, t = gm & 2047, hh = gn >> 6, dk = gn & 63;
          if (!vmode)
            D[(((size_t)(bb * 8 + hh) * TT + t) << 6) + dk] = f2h(v);  // [bh][t][dk]
          else
            D[(((size_t)(bb * 8 + hh) << 6) + dk) * TT + t] = f2h(v);  // [bh][dk][t]
        }
      }
}

// ---------------- flash attention: 512 blocks = 32 bh * 16 q-tiles(128)
__global__ __launch_bounds__(256) void k_attn(
    const u16* __restrict__ Q, const u16* __restrict__ K,
    const u16* __restrict__ Vt, const float* __restrict__ bias,
    const float* __restrict__ mask, u16* __restrict__ Y) {
  const int tid = threadIdx.x;
  const int wv = tid >> 6;
  const int lane = tid & 63;
  const int quad = lane >> 4;
  const int l16 = lane & 15;

  const int bx = blockIdx.x;
  const int bh = bx >> 4;  // 0..31
  const int qt = bx & 15;
  const int b = bh >> 3, h = bh & 7;
  const int q0 = qt * 128;

  __shared__ __align__(16) u16 Ks[64 * 64];   // K tile [s][dk]
  __shared__ __align__(16) u16 Vs[64 * 64];   // V^T tile [dk][s]
  __shared__ __align__(16) u16 Pl[128 * 72];  // P, padded stride 72

  // Preload Q fragments (A-operand: m=lane&15, k=quad*8+j), reused all tiles.
  half8 qf[2][2];
  for (int rt = 0; rt < 2; ++rt) {
    size_t qrow = (size_t)bh * TT + q0 + wv * 32 + rt * 16 + l16;
    for (int kc = 0; kc < 2; ++kc)
      qf[rt][kc] = *(const half8*)(Q + qrow * 64 + kc * 32 + quad * 8);
  }

  float m_i[2][4], l_i[2][4];
  f32x4 oacc[2][4];
  for (int rt = 0; rt < 2; ++rt)
    for (int r = 0; r < 4; ++r) { m_i[rt][r] = -1e30f; l_i[rt][r] = 0.f; }
  for (int rt = 0; rt < 2; ++rt)
    for (int ct = 0; ct < 4; ++ct) oacc[rt][ct] = (f32x4){0.f, 0.f, 0.f, 0.f};

  const size_t biasbase = (size_t)h * TT * TT;

  for (int st = 0; st < 32; ++st) {
    const int s0 = st * 64;
    for (int r = 0; r < 2; ++r) {
      int cid = r * 256 + tid;
      int row = cid >> 3, cl = cid & 7, cg = cl ^ (row & 7);
      async16(K + ((size_t)bh * TT + s0 + row) * 64 + cg * 8,
              &Ks[(r * 256 + wv * 64) * 8]);
      async16(Vt + ((size_t)(bh * 64 + row)) * TT + s0 + cg * 8,
              &Vs[(r * 256 + wv * 64) * 8]);
    }
    __syncthreads();

    float mk[4];
    for (int ct = 0; ct < 4; ++ct) mk[ct] = mask[b * TT + s0 + ct * 16 + l16];

    // S = Q @ K^T
    f32x4 sacc[2][4];
    for (int rt = 0; rt < 2; ++rt)
      for (int ct = 0; ct < 4; ++ct) sacc[rt][ct] = (f32x4){0.f, 0.f, 0.f, 0.f};
    for (int kc = 0; kc < 2; ++kc) {
      half8 bfv[4];
      for (int ct = 0; ct < 4; ++ct) {
        int row = ct * 16 + l16;
        int c = (kc * 4 + quad) ^ (row & 7);
        bfv[ct] = *(const half8*)&Ks[row * 64 + c * 8];
      }
      for (int rt = 0; rt < 2; ++rt)
        for (int ct = 0; ct < 4; ++ct)
          sacc[rt][ct] = __builtin_amdgcn_mfma_f32_16x16x32_f16(
              qf[rt][kc], bfv[ct], sacc[rt][ct], 0, 0, 0);
    }

    // Position bias loads (dominant HBM stream), C-layout gather.
    float bv[2][4][4];
    for (int rt = 0; rt < 2; ++rt) {
      int tg = q0 + wv * 32 + rt * 16 + quad * 4;
      for (int reg = 0; reg < 4; ++reg) {
        const float* bp = bias + biasbase + (size_t)(tg + reg) * TT + s0 + l16;
        for (int ct = 0; ct < 4; ++ct) bv[rt][ct][reg] = bp[ct * 16];
      }
    }

    // Online softmax; each row lives in the 16 lanes of one quad.
    for (int rt = 0; rt < 2; ++rt) {
      for (int reg = 0; reg < 4; ++reg) {
        float s[4];
        for (int ct = 0; ct < 4; ++ct)
          s[ct] = sacc[rt][ct][reg] + bv[rt][ct][reg] + mk[ct];
        float mx = fmaxf(fmaxf(s[0], s[1]), fmaxf(s[2], s[3]));
        mx = fmaxf(mx, __shfl_xor(mx, 1));
        mx = fmaxf(mx, __shfl_xor(mx, 2));
        mx = fmaxf(mx, __shfl_xor(mx, 4));
        mx = fmaxf(mx, __shfl_xor(mx, 8));
        float mold = m_i[rt][reg];
        float mnew = fmaxf(mold, mx);
        float alpha = __builtin_amdgcn_exp2f((mold - mnew) * L2E);
        float p[4], rs = 0.f;
        for (int ct = 0; ct < 4; ++ct) {
          p[ct] = __builtin_amdgcn_exp2f((s[ct] - mnew) * L2E);
          rs += p[ct];
        }
        rs += __shfl_xor(rs, 1);
        rs += __shfl_xor(rs, 2);
        rs += __shfl_xor(rs, 4);
        rs += __shfl_xor(rs, 8);
        l_i[rt][reg] = l_i[rt][reg] * alpha + rs;
        m_i[rt][reg] = mnew;
        for (int ct = 0; ct < 4; ++ct) oacc[rt][ct][reg] *= alpha;
        int prow = wv * 32 + rt * 16 + quad * 4 + reg;
        for (int ct = 0; ct < 4; ++ct) Pl[prow * 72 + ct * 16 + l16] = f2h(p[ct]);
      }
    }
    __syncthreads();

    // O += P @ V  (P as A-operand from LDS; V^T tile as B-operand)
    for (int kc = 0; kc < 2; ++kc) {
      half8 pf[2], vf[4];
      for (int rt = 0; rt < 2; ++rt)
        pf[rt] = *(const half8*)&Pl[(wv * 32 + rt * 16 + l16) * 72 + kc * 32 + quad * 8];
      for (int ct = 0; ct < 4; ++ct) {
        int row = ct * 16 + l16;
        int c = (kc * 4 + quad) ^ (row & 7);
        vf[ct] = *(const half8*)&Vs[row * 64 + c * 8];
      }
      for (int rt = 0; rt < 2; ++rt)
        for (int ct = 0; ct < 4; ++ct)
          oacc[rt][ct] = __builtin_amdgcn_mfma_f32_16x16x32_f16(
              pf[rt], vf[ct], oacc[rt][ct], 0, 0, 0);
    }
    __syncthreads();
  }

  // Epilogue: y token-major [B,T,512] f16 (feeds the output GEMM).
  for (int rt = 0; rt < 2; ++rt)
    for (int reg = 0; reg < 4; ++reg) {
      int tg = q0 + wv * 32 + rt * 16 + quad * 4 + reg;
      float inv = 1.f / l_i[rt][reg];
      for (int ct = 0; ct < 4; ++ct) {
        float v = oacc[rt][ct][reg] * inv;
        Y[((size_t)(b * TT + tg)) * DIM + h * 64 + ct * 16 + l16] = f2h(v);
      }
    }
}

extern "C" void kernel_launch(void* const* d_in, const int* in_sizes, int n_in,
                              void* d_out, int out_size, void* d_ws, size_t ws_size,
                              hipStream_t stream) {
  const float* x    = (const float*)d_in[0];
  const float* mask = (const float*)d_in[1];
  const float* bias = (const float*)d_in[2];
  const float* Wq   = (const float*)d_in[3];
  const float* Wk   = (const float*)d_in[4];
  const float* Wv   = (const float*)d_in[5];
  const float* Wo   = (const float*)d_in[6];
  (void)Wk; (void)Wv;  // consumed via contiguous weight block in ws

  // Workspace layout (f16 elements): xb | wq,wk,wv,wo | Q,K,Vt | y  (~42 MB)
  u16* xb  = (u16*)d_ws;
  u16* wb  = xb + 4194304;            // 4 * 262144
  u16* qkv = wb + 4 * 262144;         // 3 * 4194304 (Q head-major, K head-major, V^T)
  u16* yb  = qkv + 3 * (size_t)4194304;

  k_convert<<<2560, 256, 0, stream>>>(x, Wq, Wk, Wv, Wo, xb);
  k_gemm<0><<<dim3(64, 4, 3), 256, 0, stream>>>(xb, wb, qkv, nullptr);
  k_attn<<<512, 256, 0, stream>>>(qkv, qkv + 4194304, qkv + 2 * (size_t)4194304,
                                  bias, mask, yb);
  k_gemm<1><<<dim3(64, 4, 1), 256, 0, stream>>>(yb, wb + 3 * 262144, nullptr,
                                                (float*)d_out);
}

// Round 3
// 329.397 us; speedup vs baseline: 1.0431x; 1.0431x over previous
//
#include <hip/hip_runtime.h>
#include <stdint.h>

typedef unsigned short u16;
typedef __attribute__((ext_vector_type(8))) _Float16 half8;  // 8 x f16 (4 VGPRs)
typedef __attribute__((ext_vector_type(4))) float f32x4;

#define L2E 1.4426950408889634f

// B=4, T=2048, D=512, H=8, DK=64; NTOK = B*T = 8192
#define NTOK 8192
#define DIM  512
#define TT   2048

__device__ __forceinline__ u16 f2h(float f) {
  _Float16 h = (_Float16)f;  // RNE via v_cvt_f16_f32
  return __builtin_bit_cast(u16, h);
}

__device__ __forceinline__ void async16(const void* g, void* l) {
  __builtin_amdgcn_global_load_lds(
      (const __attribute__((address_space(1))) unsigned int*)g,
      (__attribute__((address_space(3))) unsigned int*)l, 16, 0, 0);
}

// ---------------- fp32 -> fp16 conversion: x (4.19M) + 4 weights (262144 each)
__global__ __launch_bounds__(256) void k_convert(
    const float* __restrict__ x, const float* __restrict__ wq,
    const float* __restrict__ wk, const float* __restrict__ wv,
    const float* __restrict__ wo, u16* __restrict__ xb) {
  size_t i = ((size_t)blockIdx.x * 256 + threadIdx.x) * 8;
  const float* src;
  u16* dst;
  size_t off;
  if (i < 4194304) {
    src = x; dst = xb; off = i;
  } else {
    size_t j = i - 4194304;
    int w = (int)(j >> 18);
    off = j & 262143;
    src = (w == 0) ? wq : (w == 1) ? wk : (w == 2) ? wv : wo;
    dst = xb + 4194304 + (size_t)w * 262144;
  }
  float4 a = *(const float4*)(src + off);
  float4 b = *(const float4*)(src + off + 4);
  uint4 pk;
  pk.x = (unsigned)f2h(a.x) | ((unsigned)f2h(a.y) << 16);
  pk.y = (unsigned)f2h(a.z) | ((unsigned)f2h(a.w) << 16);
  pk.z = (unsigned)f2h(b.x) | ((unsigned)f2h(b.y) << 16);
  pk.w = (unsigned)f2h(b.z) | ((unsigned)f2h(b.w) << 16);
  *(uint4*)(dst + off) = pk;
}

// ---------------- QKV projection GEMM, 128x128 tiles: C = x @ W^T
// VSWAP=false (Q,K): D[token][feat] -> head-major [bh][t][dk]
// VSWAP=true  (V)  : MFMA operands swapped -> D[feat][token] -> Vt [bh][dk][t]
//                    (coalesced 32B runs instead of scattered 2B stores)
template <bool VSWAP>
__global__ __launch_bounds__(256) void k_proj(
    const u16* __restrict__ A, const u16* __restrict__ Wb,
    u16* __restrict__ Db) {
  const int tid = threadIdx.x;
  const int wave = tid >> 6, lane = tid & 63;
  const int quad = lane >> 4, l16 = lane & 15;
  const int wr = wave >> 1, wc = wave & 1;
  const int m0 = blockIdx.x * 128, n0 = blockIdx.y * 128;

  const u16* W;
  u16* D;
  if (VSWAP) {
    W = Wb + 2 * 262144;            // Wv
    D = Db + 2 * (size_t)4194304;   // Vt
  } else {
    int z = blockIdx.z;
    W = Wb + (size_t)z * 262144;    // Wq / Wk
    D = Db + (size_t)z * 4194304;   // Q / K head-major
  }

  __shared__ __align__(16) u16 As[128 * 64];
  __shared__ __align__(16) u16 Bs[128 * 64];

  f32x4 acc[4][4];
  for (int rt = 0; rt < 4; ++rt)
    for (int ct = 0; ct < 4; ++ct) acc[rt][ct] = (f32x4){0.f, 0.f, 0.f, 0.f};

  for (int kb = 0; kb < 8; ++kb) {
    const int k0 = kb * 64;
    for (int r = 0; r < 4; ++r) {
      int cid = r * 256 + tid;
      int row = cid >> 3, cl = cid & 7, cg = cl ^ (row & 7);
      async16(A + (size_t)(m0 + row) * DIM + k0 + cg * 8,
              &As[(r * 256 + wave * 64) * 8]);
    }
    for (int r = 0; r < 4; ++r) {
      int cid = r * 256 + tid;
      int row = cid >> 3, cl = cid & 7, cg = cl ^ (row & 7);
      async16(W + (size_t)(n0 + row) * DIM + k0 + cg * 8,
              &Bs[(r * 256 + wave * 64) * 8]);
    }
    __syncthreads();
    for (int kc = 0; kc < 2; ++kc) {
      half8 af[4], wf[4];
      for (int rt = 0; rt < 4; ++rt) {
        int row = wr * 64 + rt * 16 + l16;
        int c = (kc * 4 + quad) ^ (row & 7);
        af[rt] = *(const half8*)&As[row * 64 + c * 8];
      }
      for (int ct = 0; ct < 4; ++ct) {
        int row = wc * 64 + ct * 16 + l16;
        int c = (kc * 4 + quad) ^ (row & 7);
        wf[ct] = *(const half8*)&Bs[row * 64 + c * 8];
      }
      for (int rt = 0; rt < 4; ++rt)
        for (int ct = 0; ct < 4; ++ct)
          acc[rt][ct] = VSWAP
              ? __builtin_amdgcn_mfma_f32_16x16x32_f16(wf[ct], af[rt],
                                                       acc[rt][ct], 0, 0, 0)
              : __builtin_amdgcn_mfma_f32_16x16x32_f16(af[rt], wf[ct],
                                                       acc[rt][ct], 0, 0, 0);
    }
    __syncthreads();
  }

  // C/D layout: col = lane&15, row = quad*4 + reg.
  for (int rt = 0; rt < 4; ++rt)
    for (int ct = 0; ct < 4; ++ct)
      for (int reg = 0; reg < 4; ++reg) {
        float v = acc[rt][ct][reg];
        if (!VSWAP) {
          int gm = m0 + wr * 64 + rt * 16 + quad * 4 + reg;  // token
          int gn = n0 + wc * 64 + ct * 16 + l16;             // feature
          int bb = gm >> 11, t = gm & 2047, hh = gn >> 6, dk = gn & 63;
          D[(((size_t)(bb * 8 + hh) * TT + t) << 6) + dk] = f2h(v);
        } else {
          int feat = n0 + wc * 64 + ct * 16 + quad * 4 + reg;  // m-dim = feature
          int tok  = m0 + wr * 64 + rt * 16 + l16;             // n-dim = token
          int bb = tok >> 11, t = tok & 2047, hh = feat >> 6, dk = feat & 63;
          D[(((size_t)(bb * 8 + hh) << 6) + dk) * TT + t] = f2h(v);
        }
      }
}

// ---------------- output GEMM: out = y @ Wo^T, 64x128 tiles, fp32 out
__global__ __launch_bounds__(256) void k_ogemm(
    const u16* __restrict__ A, const u16* __restrict__ W,
    float* __restrict__ Df) {
  const int tid = threadIdx.x;
  const int wave = tid >> 6, lane = tid & 63;
  const int quad = lane >> 4, l16 = lane & 15;
  const int wr = wave >> 1, wc = wave & 1;
  const int m0 = blockIdx.x * 64, n0 = blockIdx.y * 128;

  __shared__ __align__(16) u16 As[64 * 64];
  __shared__ __align__(16) u16 Bs[128 * 64];

  f32x4 acc[2][4];
  for (int rt = 0; rt < 2; ++rt)
    for (int ct = 0; ct < 4; ++ct) acc[rt][ct] = (f32x4){0.f, 0.f, 0.f, 0.f};

  for (int kb = 0; kb < 8; ++kb) {
    const int k0 = kb * 64;
    for (int r = 0; r < 2; ++r) {
      int cid = r * 256 + tid;
      int row = cid >> 3, cl = cid & 7, cg = cl ^ (row & 7);
      async16(A + (size_t)(m0 + row) * DIM + k0 + cg * 8,
              &As[(r * 256 + wave * 64) * 8]);
    }
    for (int r = 0; r < 4; ++r) {
      int cid = r * 256 + tid;
      int row = cid >> 3, cl = cid & 7, cg = cl ^ (row & 7);
      async16(W + (size_t)(n0 + row) * DIM + k0 + cg * 8,
              &Bs[(r * 256 + wave * 64) * 8]);
    }
    __syncthreads();
    for (int kc = 0; kc < 2; ++kc) {
      half8 af[2], wf[4];
      for (int rt = 0; rt < 2; ++rt) {
        int row = wr * 32 + rt * 16 + l16;
        int c = (kc * 4 + quad) ^ (row & 7);
        af[rt] = *(const half8*)&As[row * 64 + c * 8];
      }
      for (int ct = 0; ct < 4; ++ct) {
        int row = wc * 64 + ct * 16 + l16;
        int c = (kc * 4 + quad) ^ (row & 7);
        wf[ct] = *(const half8*)&Bs[row * 64 + c * 8];
      }
      for (int rt = 0; rt < 2; ++rt)
        for (int ct = 0; ct < 4; ++ct)
          acc[rt][ct] = __builtin_amdgcn_mfma_f32_16x16x32_f16(
              af[rt], wf[ct], acc[rt][ct], 0, 0, 0);
    }
    __syncthreads();
  }

  for (int rt = 0; rt < 2; ++rt)
    for (int ct = 0; ct < 4; ++ct)
      for (int reg = 0; reg < 4; ++reg) {
        int gm = m0 + wr * 32 + rt * 16 + quad * 4 + reg;
        int gn = n0 + wc * 64 + ct * 16 + l16;
        Df[(size_t)gm * DIM + gn] = acc[rt][ct][reg];
      }
}

// ---------------- flash attention: 1024 blocks = 32 bh * 32 q-tiles(64 rows)
__global__ __launch_bounds__(256) void k_attn(
    const u16* __restrict__ Q, const u16* __restrict__ K,
    const u16* __restrict__ Vt, const float* __restrict__ bias,
    const float* __restrict__ mask, u16* __restrict__ Y) {
  const int tid = threadIdx.x;
  const int wv = tid >> 6;
  const int lane = tid & 63;
  const int quad = lane >> 4;
  const int l16 = lane & 15;

  const int bx = blockIdx.x;
  const int bh = bx >> 5;  // 0..31
  const int qt = bx & 31;
  const int b = bh >> 3, h = bh & 7;
  const int q0 = qt * 64;

  __shared__ __align__(16) u16 Ks[64 * 64];  // K tile [s][dk]
  __shared__ __align__(16) u16 Vs[64 * 64];  // V^T tile [dk][s]
  __shared__ __align__(16) u16 Pl[64 * 72];  // P, padded stride 72

  // Q fragments (A-operand: m=lane&15, k=quad*8+j); wave wv owns rows wv*16..+15
  half8 qf[2];
  {
    size_t qrow = (size_t)bh * TT + q0 + wv * 16 + l16;
    for (int kc = 0; kc < 2; ++kc)
      qf[kc] = *(const half8*)(Q + qrow * 64 + kc * 32 + quad * 8);
  }

  float m_i[4], l_i[4];
  f32x4 oacc[4];
  for (int r = 0; r < 4; ++r) { m_i[r] = -1e30f; l_i[r] = 0.f; }
  for (int ct = 0; ct < 4; ++ct) oacc[ct] = (f32x4){0.f, 0.f, 0.f, 0.f};

  const size_t biasbase = (size_t)h * TT * TT;

  for (int st = 0; st < 32; ++st) {
    const int s0 = st * 64;
    for (int r = 0; r < 2; ++r) {
      int cid = r * 256 + tid;
      int row = cid >> 3, cl = cid & 7, cg = cl ^ (row & 7);
      async16(K + ((size_t)bh * TT + s0 + row) * 64 + cg * 8,
              &Ks[(r * 256 + wv * 64) * 8]);
      async16(Vt + ((size_t)(bh * 64 + row)) * TT + s0 + cg * 8,
              &Vs[(r * 256 + wv * 64) * 8]);
    }
    __syncthreads();

    float mk[4];
    for (int ct = 0; ct < 4; ++ct) mk[ct] = mask[b * TT + s0 + ct * 16 + l16];

    // S = Q @ K^T
    f32x4 sacc[4];
    for (int ct = 0; ct < 4; ++ct) sacc[ct] = (f32x4){0.f, 0.f, 0.f, 0.f};
    for (int kc = 0; kc < 2; ++kc) {
      half8 kf[4];
      for (int ct = 0; ct < 4; ++ct) {
        int row = ct * 16 + l16;
        int c = (kc * 4 + quad) ^ (row & 7);
        kf[ct] = *(const half8*)&Ks[row * 64 + c * 8];
      }
      for (int ct = 0; ct < 4; ++ct)
        sacc[ct] = __builtin_amdgcn_mfma_f32_16x16x32_f16(
            qf[kc], kf[ct], sacc[ct], 0, 0, 0);
    }

    // Position bias (dominant HBM stream), C-layout gather.
    float bv[4][4];
    {
      int tg = q0 + wv * 16 + quad * 4;
      for (int reg = 0; reg < 4; ++reg) {
        const float* bp = bias + biasbase + (size_t)(tg + reg) * TT + s0 + l16;
        for (int ct = 0; ct < 4; ++ct) bv[ct][reg] = bp[ct * 16];
      }
    }

    // Online softmax; each row lives in the 16 lanes of one quad.
    for (int reg = 0; reg < 4; ++reg) {
      float s[4];
      for (int ct = 0; ct < 4; ++ct)
        s[ct] = sacc[ct][reg] + bv[ct][reg] + mk[ct];
      float mx = fmaxf(fmaxf(s[0], s[1]), fmaxf(s[2], s[3]));
      mx = fmaxf(mx, __shfl_xor(mx, 1));
      mx = fmaxf(mx, __shfl_xor(mx, 2));
      mx = fmaxf(mx, __shfl_xor(mx, 4));
      mx = fmaxf(mx, __shfl_xor(mx, 8));
      float mold = m_i[reg];
      float mnew = fmaxf(mold, mx);
      float alpha = __builtin_amdgcn_exp2f((mold - mnew) * L2E);
      float p[4], rs = 0.f;
      for (int ct = 0; ct < 4; ++ct) {
        p[ct] = __builtin_amdgcn_exp2f((s[ct] - mnew) * L2E);
        rs += p[ct];
      }
      rs += __shfl_xor(rs, 1);
      rs += __shfl_xor(rs, 2);
      rs += __shfl_xor(rs, 4);
      rs += __shfl_xor(rs, 8);
      l_i[reg] = l_i[reg] * alpha + rs;
      m_i[reg] = mnew;
      for (int ct = 0; ct < 4; ++ct) oacc[ct][reg] *= alpha;
      int prow = wv * 16 + quad * 4 + reg;
      for (int ct = 0; ct < 4; ++ct) Pl[prow * 72 + ct * 16 + l16] = f2h(p[ct]);
    }
    __syncthreads();

    // O += P @ V  (P as A-operand from LDS; V^T tile as B-operand)
    for (int kc = 0; kc < 2; ++kc) {
      half8 pf, vf[4];
      pf = *(const half8*)&Pl[(wv * 16 + l16) * 72 + kc * 32 + quad * 8];
      for (int ct = 0; ct < 4; ++ct) {
        int row = ct * 16 + l16;
        int c = (kc * 4 + quad) ^ (row & 7);
        vf[ct] = *(const half8*)&Vs[row * 64 + c * 8];
      }
      for (int ct = 0; ct < 4; ++ct)
        oacc[ct] = __builtin_amdgcn_mfma_f32_16x16x32_f16(
            pf, vf[ct], oacc[ct], 0, 0, 0);
    }
    __syncthreads();
  }

  // Epilogue: y token-major [B,T,512] f16 (feeds the output GEMM).
  for (int reg = 0; reg < 4; ++reg) {
    int tg = q0 + wv * 16 + quad * 4 + reg;
    float inv = 1.f / l_i[reg];
    for (int ct = 0; ct < 4; ++ct) {
      float v = oacc[ct][reg] * inv;
      Y[((size_t)(b * TT + tg)) * DIM + h * 64 + ct * 16 + l16] = f2h(v);
    }
  }
}

extern "C" void kernel_launch(void* const* d_in, const int* in_sizes, int n_in,
                              void* d_out, int out_size, void* d_ws, size_t ws_size,
                              hipStream_t stream) {
  const float* x    = (const float*)d_in[0];
  const float* mask = (const float*)d_in[1];
  const float* bias = (const float*)d_in[2];
  const float* Wq   = (const float*)d_in[3];
  const float* Wk   = (const float*)d_in[4];
  const float* Wv   = (const float*)d_in[5];
  const float* Wo   = (const float*)d_in[6];
  (void)Wk; (void)Wv;  // consumed via contiguous weight block in ws

  // Workspace (f16 elems): xb | wq,wk,wv,wo | Q,K,Vt | y  (~44 MB)
  u16* xb  = (u16*)d_ws;
  u16* wb  = xb + 4194304;            // 4 * 262144
  u16* qkv = wb + 4 * 262144;         // Q, K head-major; V^T
  u16* yb  = qkv + 3 * (size_t)4194304;

  k_convert<<<2560, 256, 0, stream>>>(x, Wq, Wk, Wv, Wo, xb);
  k_proj<false><<<dim3(64, 4, 2), 256, 0, stream>>>(xb, wb, qkv);
  k_proj<true><<<dim3(64, 4), 256, 0, stream>>>(xb, wb, qkv);
  k_attn<<<1024, 256, 0, stream>>>(qkv, qkv + 4194304,
                                   qkv + 2 * (size_t)4194304, bias, mask, yb);
  k_ogemm<<<dim3(128, 4), 256, 0, stream>>>(yb, wb + 3 * 262144, (float*)d_out);
}